// Round 4
// baseline (183.901 us; speedup 1.0000x reference)
//
#include <hip/hip_runtime.h>

// ---- types ----
typedef __bf16 bf16x8 __attribute__((ext_vector_type(8)));
typedef float  f32x4  __attribute__((ext_vector_type(4)));

__device__ __forceinline__ short f2bf(float f) {
  union { float f; unsigned u; } v; v.f = f;
  unsigned r = v.u + 0x7fffu + ((v.u >> 16) & 1u);
  return (short)(r >> 16);
}

// async global->LDS (16B per lane); LDS dest must be wave-uniform base + lane*16
__device__ __forceinline__ void gl_lds16(const short* g, short* l) {
  __builtin_amdgcn_global_load_lds((const __attribute__((address_space(1))) void*)g,
                                   (__attribute__((address_space(3))) void*)l, 16, 0, 0);
}

// ---- cast x fp32 -> bf16 (vectorized) ----
__global__ __launch_bounds__(256) void cast_x_kernel(const float* __restrict__ in,
                                                     short* __restrict__ out, int n4) {
  int i = blockIdx.x * 256 + threadIdx.x;
  if (i >= n4) return;
  float4 f = reinterpret_cast<const float4*>(in)[i];
  short4 o;
  o.x = f2bf(f.x); o.y = f2bf(f.y); o.z = f2bf(f.z); o.w = f2bf(f.w);
  reinterpret_cast<short4*>(out)[i] = o;
}

// ---- transpose + cast: in[R][Cc] fp32 -> out[Cc][R] bf16 ----
__global__ __launch_bounds__(256) void transpose_cast(const float* __restrict__ in,
                                                      short* __restrict__ out, int R, int Cc) {
  __shared__ short tile[64][65];
  int bx = blockIdx.x * 64;
  int by = blockIdx.y * 64;
  int tx = threadIdx.x & 63, ty = threadIdx.x >> 6;
  #pragma unroll
  for (int i = ty; i < 64; i += 4)
    tile[i][tx] = f2bf(in[(size_t)(by + i) * Cc + bx + tx]);
  __syncthreads();
  #pragma unroll
  for (int i = ty; i < 64; i += 4)
    out[(size_t)(bx + i) * R + by + tx] = tile[tx][i];
}

// ---- GEMM1: qkv = x_bf[4096][1024] * Wqkv_t[3072][1024]^T + bqkv
//      q,k -> [B2][H16][T2048][D64] bf16 (q scaled 0.125*log2e); v -> [BH][D64][T2048]
__global__ __launch_bounds__(256) void gemm_qkv(const short* __restrict__ A,
                                                const short* __restrict__ Bt,
                                                const float* __restrict__ bias,
                                                short* __restrict__ qo,
                                                short* __restrict__ ko,
                                                short* __restrict__ vt) {
  const int K = 1024;
  __shared__ short Al[8192];   // linear [128][64]
  __shared__ short Bl[8192];
  int tid = threadIdx.x;
  int mtile = blockIdx.y * 128, ntile = blockIdx.x * 128;
  int w = tid >> 6, l = tid & 63;
  int wr = w >> 1, wc = w & 1;
  int lr = l & 15, lg = l >> 4;

  f32x4 zero4 = {0.f, 0.f, 0.f, 0.f};
  f32x4 acc[4][4];
  #pragma unroll
  for (int i = 0; i < 4; ++i)
    #pragma unroll
    for (int j = 0; j < 4; ++j) acc[i][j] = zero4;

  for (int k0 = 0; k0 < K; k0 += 64) {
    __syncthreads();
    #pragma unroll
    for (int c = 0; c < 4; ++c) {
      int idx = tid + c * 256;
      int row = idx >> 3, kc = idx & 7;
      gl_lds16(&A[(size_t)(mtile + row) * K + k0 + kc * 8], &Al[idx * 8]);
      gl_lds16(&Bt[(size_t)(ntile + row) * K + k0 + kc * 8], &Bl[idx * 8]);
    }
    __syncthreads();
    __builtin_amdgcn_s_setprio(1);
    #pragma unroll
    for (int kk = 0; kk < 2; ++kk) {
      bf16x8 af[4], bfr[4];
      #pragma unroll
      for (int i = 0; i < 4; ++i)
        af[i] = *reinterpret_cast<const bf16x8*>(&Al[(wr * 64 + i * 16 + lr) * 64 + kk * 32 + lg * 8]);
      #pragma unroll
      for (int j = 0; j < 4; ++j)
        bfr[j] = *reinterpret_cast<const bf16x8*>(&Bl[(wc * 64 + j * 16 + lr) * 64 + kk * 32 + lg * 8]);
      #pragma unroll
      for (int i = 0; i < 4; ++i)
        #pragma unroll
        for (int j = 0; j < 4; ++j)
          acc[i][j] = __builtin_amdgcn_mfma_f32_16x16x32_bf16(af[i], bfr[j], acc[i][j], 0, 0, 0);
    }
    __builtin_amdgcn_s_setprio(0);
  }

  #pragma unroll
  for (int j = 0; j < 4; ++j) {
    int n = ntile + wc * 64 + j * 16 + lr;   // 0..3071 (sec uniform per block)
    float bv = bias[n];
    int sec = n >> 10;
    int ch = n & 1023;
    int h = ch >> 6, d = ch & 63;
    if (sec == 2) {
      #pragma unroll
      for (int i = 0; i < 4; ++i) {
        int t0g = mtile + wr * 64 + i * 16 + lg * 4;
        int bb = t0g >> 11, t = t0g & 2047;
        short4 pk;
        pk.x = f2bf(acc[i][j][0] + bv);
        pk.y = f2bf(acc[i][j][1] + bv);
        pk.z = f2bf(acc[i][j][2] + bv);
        pk.w = f2bf(acc[i][j][3] + bv);
        *reinterpret_cast<short4*>(&vt[((size_t)(bb * 16 + h) * 64 + d) * 2048 + t]) = pk;
      }
    } else {
      short* dst = (sec == 0) ? qo : ko;
      // q scaled by (1/sqrt(64)) * log2(e) so attention works in exp2 domain
      float sc = (sec == 0) ? 0.18033688f : 1.0f;
      #pragma unroll
      for (int i = 0; i < 4; ++i) {
        #pragma unroll
        for (int r = 0; r < 4; ++r) {
          int m = mtile + wr * 64 + i * 16 + lg * 4 + r;
          int bb = m >> 11, t = m & 2047;
          dst[(size_t)((bb * 16 + h) * 2048 + t) * 64 + d] = f2bf((acc[i][j][r] + bv) * sc);
        }
      }
    }
  }
}

// ---- attention core: one 128-kv-wide pass (S + single softmax + PV) ----
// NS = number of 64-subtiles (1 or 2); DS = diagonal subtile index (-1 none)
template<int NS, int DS>
__device__ __forceinline__ void proc128(const short* __restrict__ Kb,
                                        const short* __restrict__ Vb,
                                        short* __restrict__ Pl,
                                        const bf16x8* qa,
                                        float& MI, float& LI, f32x4* YT,
                                        int w, int lr, int lg) {
  const f32x4 zero4 = {0.f, 0.f, 0.f, 0.f};
  f32x4 s[NS * 4];
  #pragma unroll
  for (int i = 0; i < NS * 4; ++i) s[i] = zero4;

  __builtin_amdgcn_s_setprio(1);
  #pragma unroll
  for (int sub = 0; sub < NS; ++sub)
    #pragma unroll
    for (int g = 0; g < 4; ++g)
      #pragma unroll
      for (int kk = 0; kk < 2; ++kk) {
        bf16x8 kf = *reinterpret_cast<const bf16x8*>(
            &Kb[sub * 4096 + (g * 16 + lr) * 64 + (((kk * 4 + lg) ^ (lr & 7)) * 8)]);
        s[sub * 4 + g] = __builtin_amdgcn_mfma_f32_16x16x32_bf16(kf, qa[kk], s[sub * 4 + g], 0, 0, 0);
      }
  __builtin_amdgcn_s_setprio(0);

  if (DS >= 0) {
    #pragma unroll
    for (int g = 0; g < 4; ++g)
      #pragma unroll
      for (int r = 0; r < 4; ++r)
        if (g * 16 + lg * 4 + r > w * 16 + lr) s[DS * 4 + g][r] = -1e30f;
  }

  // row max (tree + 2 shfl)
  float pm;
  {
    float t[NS * 4];
    #pragma unroll
    for (int i = 0; i < NS * 4; ++i)
      t[i] = fmaxf(fmaxf(s[i][0], s[i][1]), fmaxf(s[i][2], s[i][3]));
    float a = fmaxf(fmaxf(t[0], t[1]), fmaxf(t[2], t[3]));
    if (NS == 2) a = fmaxf(a, fmaxf(fmaxf(t[4], t[5]), fmaxf(t[6], t[7])));
    a = fmaxf(a, __shfl_xor(a, 16));
    pm = fmaxf(a, __shfl_xor(a, 32));
  }
  // defer-max: only rescale when tile max grew past threshold (log2 units)
  if (!__all(pm - MI <= 8.0f)) {
    float mnew = fmaxf(MI, pm);
    float scl = exp2f(MI - mnew);
    MI = mnew;
    LI *= scl;
    #pragma unroll
    for (int gd = 0; gd < 4; ++gd)
      #pragma unroll
      for (int r = 0; r < 4; ++r) YT[gd][r] *= scl;
  }
  float rsub[NS * 4];
  #pragma unroll
  for (int i = 0; i < NS * 4; ++i) {
    #pragma unroll
    for (int r = 0; r < 4; ++r) s[i][r] = exp2f(s[i][r] - MI);
    rsub[i] = (s[i][0] + s[i][1]) + (s[i][2] + s[i][3]);
  }
  float rs = (rsub[0] + rsub[1]) + (rsub[2] + rsub[3]);
  if (NS == 2) rs += (rsub[4] + rsub[5]) + (rsub[6] + rsub[7]);
  rs += __shfl_xor(rs, 16);
  rs += __shfl_xor(rs, 32);
  LI += rs;

  // pack P -> per-wave swizzled LDS (8B half-chunks, h' = h ^ ((lr&7)<<1))
  #pragma unroll
  for (int i = 0; i < NS * 4; ++i) {
    uint2 pk;
    pk.x = (unsigned)(unsigned short)f2bf(s[i][0]) |
           ((unsigned)(unsigned short)f2bf(s[i][1]) << 16);
    pk.y = (unsigned)(unsigned short)f2bf(s[i][2]) |
           ((unsigned)(unsigned short)f2bf(s[i][3]) << 16);
    int h = (i * 4 + lg) ^ ((lr & 7) << 1);
    *reinterpret_cast<uint2*>(&Pl[lr * 128 + h * 4]) = pk;
  }
  bf16x8 pa[NS * 2];
  #pragma unroll
  for (int kk = 0; kk < NS * 2; ++kk) {
    int c = (kk * 4 + lg) ^ (lr & 7);
    pa[kk] = *reinterpret_cast<const bf16x8*>(&Pl[lr * 128 + c * 8]);
  }
  __builtin_amdgcn_s_setprio(1);
  #pragma unroll
  for (int gd = 0; gd < 4; ++gd)
    #pragma unroll
    for (int kk = 0; kk < NS * 2; ++kk) {
      const int sub = kk >> 1, kx = kk & 1;
      bf16x8 vf = *reinterpret_cast<const bf16x8*>(
          &Vb[sub * 4096 + (gd * 16 + lr) * 64 + (((kx * 4 + lg) ^ (lr & 7)) * 8)]);
      YT[gd] = __builtin_amdgcn_mfma_f32_16x16x32_bf16(vf, pa[kk], YT[gd], 0, 0, 0);
    }
  __builtin_amdgcn_s_setprio(0);
}

// ---- flash attention v4: 128-wide softmax, exp2 domain, defer-max, swizzled P ----
__global__ __launch_bounds__(256) void attn_kernel(const short* __restrict__ q,
                                                   const short* __restrict__ k,
                                                   const short* __restrict__ vt,
                                                   short* __restrict__ y) {
  __shared__ short Ks[2][2][4096];   // [buf][subtile][row][slot^(row&7)][8]
  __shared__ short Vs[2][2][4096];
  __shared__ short Plds[4][2048];    // per-wave [16 rows][128], XOR-swizzled
  const int tid = threadIdx.x;
  const int w = tid >> 6, l = tid & 63, lr = l & 15, lg = l >> 4;
  int fid = blockIdx.y * 16 + blockIdx.x;
  int vid = (fid & 7) * 64 + (fid >> 3);
  const int bh = vid >> 4;
  const int j = vid & 15;
  const int hi = 31 - j;
  const int niter = (33 - j) >> 1;
  const short* qb = q + (size_t)bh * 131072;
  const short* kb = k + (size_t)bh * 131072;
  const short* vtb = vt + (size_t)bh * 131072;
  short* Pw = Plds[w];

  bf16x8 qhi[2], qlo[2];
  {
    int r1 = hi * 64 + w * 16 + lr, r2 = j * 64 + w * 16 + lr;
    #pragma unroll
    for (int kk = 0; kk < 2; ++kk) {
      qhi[kk] = *reinterpret_cast<const bf16x8*>(&qb[(size_t)r1 * 64 + kk * 32 + lg * 8]);
      qlo[kk] = *reinterpret_cast<const bf16x8*>(&qb[(size_t)r2 * 64 + kk * 32 + lg * 8]);
    }
  }

  const f32x4 zero4 = {0.f, 0.f, 0.f, 0.f};
  float mh = -1e30f, lh = 0.f, ml = -1e30f, llo = 0.f;
  f32x4 yh[4], yl[4];
  #pragma unroll
  for (int gd = 0; gd < 4; ++gd) { yh[gd] = zero4; yl[gd] = zero4; }

  const int krow = tid >> 1;
  const int ksub = krow >> 6, krow6 = krow & 63;
  const int vd = tid >> 2;
  uint4 kreg[4], vreg[4];

#define LOADT(IT) do {                                                               \
    int kv0_ = (IT) * 128;                                                           \
    _Pragma("unroll")                                                                \
    for (int c = 0; c < 4; ++c) {                                                    \
      kreg[c] = *reinterpret_cast<const uint4*>(&kb[(size_t)(kv0_ + krow) * 64 + ((tid & 1) * 4 + c) * 8]); \
      vreg[c] = *reinterpret_cast<const uint4*>(&vtb[(size_t)vd * 2048 + kv0_ + ((tid & 3) * 4 + c) * 8]);  \
    }                                                                                \
  } while (0)

#define STORET(BUF) do {                                                             \
    _Pragma("unroll")                                                                \
    for (int c = 0; c < 4; ++c) {                                                    \
      int ks_ = (tid & 1) * 4 + c;                                                   \
      *reinterpret_cast<uint4*>(&Ks[BUF][ksub][krow6 * 64 + (ks_ ^ (krow6 & 7)) * 8]) = kreg[c]; \
      int ch_ = (tid & 3) * 4 + c;                                                   \
      *reinterpret_cast<uint4*>(&Vs[BUF][ch_ >> 3][vd * 64 + ((ch_ & 7) ^ (vd & 7)) * 8]) = vreg[c]; \
    }                                                                                \
  } while (0)

  LOADT(0);
  STORET(0);
  for (int it = 0; it < niter; ++it) {
    __syncthreads();
    int buf = it & 1;
    bool pre = (it + 1 < niter);
    if (pre) LOADT(it + 1);
    int t0 = it * 2, t1 = t0 + 1;
    const short* Kb = &Ks[buf][0][0];
    const short* Vb = &Vs[buf][0][0];
    // hi q-tile (tiles 0..hi)
    if (t1 < hi)       proc128<2, -1>(Kb, Vb, Pw, qhi, mh, lh, yh, w, lr, lg);
    else if (t1 == hi) proc128<2,  1>(Kb, Vb, Pw, qhi, mh, lh, yh, w, lr, lg);
    else               proc128<1,  0>(Kb, Vb, Pw, qhi, mh, lh, yh, w, lr, lg); // t0 == hi
    // lo q-tile (tiles 0..j)
    if (t1 < j)        proc128<2, -1>(Kb, Vb, Pw, qlo, ml, llo, yl, w, lr, lg);
    else if (t1 == j)  proc128<2,  1>(Kb, Vb, Pw, qlo, ml, llo, yl, w, lr, lg);
    else if (t0 == j)  proc128<1,  0>(Kb, Vb, Pw, qlo, ml, llo, yl, w, lr, lg);
    if (pre) STORET(buf ^ 1);
  }

  int b_ = bh >> 4, h_ = bh & 15;
#define WOUT(LI, YT, QT) do {                                                        \
    float inv_ = 1.0f / (LI);                                                        \
    int qrow_ = (QT) * 64 + w * 16 + lr;                                             \
    _Pragma("unroll")                                                                \
    for (int gd = 0; gd < 4; ++gd) {                                                 \
      short4 pk_;                                                                    \
      pk_.x = f2bf((YT)[gd][0] * inv_);                                              \
      pk_.y = f2bf((YT)[gd][1] * inv_);                                              \
      pk_.z = f2bf((YT)[gd][2] * inv_);                                              \
      pk_.w = f2bf((YT)[gd][3] * inv_);                                              \
      *reinterpret_cast<short4*>(                                                    \
          &y[(size_t)(b_ * 2048 + qrow_) * 1024 + h_ * 64 + gd * 16 + lg * 4]) = pk_;\
    }                                                                                \
  } while (0)

  WOUT(lh, yh, hi);
  WOUT(llo, yl, j);
#undef LOADT
#undef STORET
#undef WOUT
}

// ---- GEMM3: out fp32 = y_bf[4096][1024] * Wproj_t[1024][1024]^T + bproj ----
__global__ __launch_bounds__(256) void gemm_proj(const short* __restrict__ A,
                                                 const short* __restrict__ Bt,
                                                 const float* __restrict__ bias,
                                                 float* __restrict__ out) {
  const int K = 1024;
  __shared__ short Al[8192];
  __shared__ short Bl[8192];
  int tid = threadIdx.x;
  int mtile = blockIdx.y * 128, ntile = blockIdx.x * 128;
  int w = tid >> 6, l = tid & 63;
  int wr = w >> 1, wc = w & 1;
  int lr = l & 15, lg = l >> 4;

  f32x4 zero4 = {0.f, 0.f, 0.f, 0.f};
  f32x4 acc[4][4];
  #pragma unroll
  for (int i = 0; i < 4; ++i)
    #pragma unroll
    for (int j = 0; j < 4; ++j) acc[i][j] = zero4;

  for (int k0 = 0; k0 < K; k0 += 64) {
    __syncthreads();
    #pragma unroll
    for (int c = 0; c < 4; ++c) {
      int idx = tid + c * 256;
      int row = idx >> 3, kc = idx & 7;
      gl_lds16(&A[(size_t)(mtile + row) * K + k0 + kc * 8], &Al[idx * 8]);
      gl_lds16(&Bt[(size_t)(ntile + row) * K + k0 + kc * 8], &Bl[idx * 8]);
    }
    __syncthreads();
    __builtin_amdgcn_s_setprio(1);
    #pragma unroll
    for (int kk = 0; kk < 2; ++kk) {
      bf16x8 af[4], bfr[4];
      #pragma unroll
      for (int i = 0; i < 4; ++i)
        af[i] = *reinterpret_cast<const bf16x8*>(&Al[(wr * 64 + i * 16 + lr) * 64 + kk * 32 + lg * 8]);
      #pragma unroll
      for (int j = 0; j < 4; ++j)
        bfr[j] = *reinterpret_cast<const bf16x8*>(&Bl[(wc * 64 + j * 16 + lr) * 64 + kk * 32 + lg * 8]);
      #pragma unroll
      for (int i = 0; i < 4; ++i)
        #pragma unroll
        for (int j = 0; j < 4; ++j)
          acc[i][j] = __builtin_amdgcn_mfma_f32_16x16x32_bf16(af[i], bfr[j], acc[i][j], 0, 0, 0);
    }
    __builtin_amdgcn_s_setprio(0);
  }

  #pragma unroll
  for (int j = 0; j < 4; ++j) {
    int n = ntile + wc * 64 + j * 16 + lr;
    float bv = bias[n];
    #pragma unroll
    for (int i = 0; i < 4; ++i) {
      #pragma unroll
      for (int r = 0; r < 4; ++r) {
        int m = mtile + wr * 64 + i * 16 + lg * 4 + r;
        out[(size_t)m * 1024 + n] = acc[i][j][r] + bv;
      }
    }
  }
}

extern "C" void kernel_launch(void* const* d_in, const int* in_sizes, int n_in,
                              void* d_out, int out_size, void* d_ws, size_t ws_size,
                              hipStream_t stream) {
  const float* x     = (const float*)d_in[0];
  const float* Wqkv  = (const float*)d_in[1];
  const float* bqkv  = (const float*)d_in[2];
  const float* Wproj = (const float*)d_in[3];
  const float* bproj = (const float*)d_in[4];
  float* out = (float*)d_out;

  const size_t M4 = 4096ull * 1024ull;
  short* ws = (short*)d_ws;
  short* x_bf    = ws;
  short* wqkv_t  = ws + M4;
  short* wproj_t = ws + M4 + 3ull * 1024 * 1024;
  short* qb      = wproj_t + 1024ull * 1024;
  short* kb      = qb + M4;
  short* vtb     = kb + M4;     // [bh][64][2048] transposed V
  short* yb      = x_bf;        // alias: x_bf dead after gemm_qkv

  cast_x_kernel<<<4096, 256, 0, stream>>>(x, x_bf, (int)(M4 / 4));
  transpose_cast<<<dim3(48, 16), 256, 0, stream>>>(Wqkv, wqkv_t, 1024, 3072);
  transpose_cast<<<dim3(16, 16), 256, 0, stream>>>(Wproj, wproj_t, 1024, 1024);
  gemm_qkv<<<dim3(24, 32), 256, 0, stream>>>(x_bf, wqkv_t, bqkv, qb, kb, vtb);
  attn_kernel<<<dim3(16, 32), 256, 0, stream>>>(qb, kb, vtb, yb);
  gemm_proj<<<dim3(8, 32), 256, 0, stream>>>(yb, wproj_t, bproj, out);
}

// Round 6
// 182.098 us; speedup vs baseline: 1.0099x; 1.0099x over previous
//
#include <hip/hip_runtime.h>

// ---- types ----
typedef __bf16 bf16x8 __attribute__((ext_vector_type(8)));
typedef float  f32x4  __attribute__((ext_vector_type(4)));
typedef float  f32x16 __attribute__((ext_vector_type(16)));
typedef unsigned int uint32x4 __attribute__((ext_vector_type(4)));

__device__ __forceinline__ short f2bf(float f) {
  union { float f; unsigned u; } v; v.f = f;
  unsigned r = v.u + 0x7fffu + ((v.u >> 16) & 1u);
  return (short)(r >> 16);
}

// async global->LDS (16B per lane); LDS dest must be wave-uniform base + lane*16
__device__ __forceinline__ void gl_lds16(const short* g, short* l) {
  __builtin_amdgcn_global_load_lds((const __attribute__((address_space(1))) void*)g,
                                   (__attribute__((address_space(3))) void*)l, 16, 0, 0);
}

// ---- cast x fp32 -> bf16 (vectorized) ----
__global__ __launch_bounds__(256) void cast_x_kernel(const float* __restrict__ in,
                                                     short* __restrict__ out, int n4) {
  int i = blockIdx.x * 256 + threadIdx.x;
  if (i >= n4) return;
  float4 f = reinterpret_cast<const float4*>(in)[i];
  short4 o;
  o.x = f2bf(f.x); o.y = f2bf(f.y); o.z = f2bf(f.z); o.w = f2bf(f.w);
  reinterpret_cast<short4*>(out)[i] = o;
}

// ---- transpose + cast: in[R][Cc] fp32 -> out[Cc][R] bf16 ----
__global__ __launch_bounds__(256) void transpose_cast(const float* __restrict__ in,
                                                      short* __restrict__ out, int R, int Cc) {
  __shared__ short tile[64][65];
  int bx = blockIdx.x * 64;
  int by = blockIdx.y * 64;
  int tx = threadIdx.x & 63, ty = threadIdx.x >> 6;
  #pragma unroll
  for (int i = ty; i < 64; i += 4)
    tile[i][tx] = f2bf(in[(size_t)(by + i) * Cc + bx + tx]);
  __syncthreads();
  #pragma unroll
  for (int i = ty; i < 64; i += 4)
    out[(size_t)(bx + i) * R + by + tx] = tile[tx][i];
}

// ---- GEMM1: qkv = x_bf[4096][1024] * Wqkv_t[3072][1024]^T + bqkv
//      q,k -> [B2][H16][T2048][D64] bf16 (q scaled 0.125*log2e); v -> [BH][D64][T2048]
__global__ __launch_bounds__(256) void gemm_qkv(const short* __restrict__ A,
                                                const short* __restrict__ Bt,
                                                const float* __restrict__ bias,
                                                short* __restrict__ qo,
                                                short* __restrict__ ko,
                                                short* __restrict__ vt) {
  const int K = 1024;
  __shared__ short Al[8192];   // linear [128][64]
  __shared__ short Bl[8192];
  int tid = threadIdx.x;
  int mtile = blockIdx.y * 128, ntile = blockIdx.x * 128;
  int w = tid >> 6, l = tid & 63;
  int wr = w >> 1, wc = w & 1;
  int lr = l & 15, lg = l >> 4;

  f32x4 zero4 = {0.f, 0.f, 0.f, 0.f};
  f32x4 acc[4][4];
  #pragma unroll
  for (int i = 0; i < 4; ++i)
    #pragma unroll
    for (int j = 0; j < 4; ++j) acc[i][j] = zero4;

  for (int k0 = 0; k0 < K; k0 += 64) {
    __syncthreads();
    #pragma unroll
    for (int c = 0; c < 4; ++c) {
      int idx = tid + c * 256;
      int row = idx >> 3, kc = idx & 7;
      gl_lds16(&A[(size_t)(mtile + row) * K + k0 + kc * 8], &Al[idx * 8]);
      gl_lds16(&Bt[(size_t)(ntile + row) * K + k0 + kc * 8], &Bl[idx * 8]);
    }
    __syncthreads();
    __builtin_amdgcn_s_setprio(1);
    #pragma unroll
    for (int kk = 0; kk < 2; ++kk) {
      bf16x8 af[4], bfr[4];
      #pragma unroll
      for (int i = 0; i < 4; ++i)
        af[i] = *reinterpret_cast<const bf16x8*>(&Al[(wr * 64 + i * 16 + lr) * 64 + kk * 32 + lg * 8]);
      #pragma unroll
      for (int j = 0; j < 4; ++j)
        bfr[j] = *reinterpret_cast<const bf16x8*>(&Bl[(wc * 64 + j * 16 + lr) * 64 + kk * 32 + lg * 8]);
      #pragma unroll
      for (int i = 0; i < 4; ++i)
        #pragma unroll
        for (int j = 0; j < 4; ++j)
          acc[i][j] = __builtin_amdgcn_mfma_f32_16x16x32_bf16(af[i], bfr[j], acc[i][j], 0, 0, 0);
    }
    __builtin_amdgcn_s_setprio(0);
  }

  #pragma unroll
  for (int j = 0; j < 4; ++j) {
    int n = ntile + wc * 64 + j * 16 + lr;   // 0..3071 (sec uniform per block)
    float bv = bias[n];
    int sec = n >> 10;
    int ch = n & 1023;
    int h = ch >> 6, d = ch & 63;
    if (sec == 2) {
      #pragma unroll
      for (int i = 0; i < 4; ++i) {
        int t0g = mtile + wr * 64 + i * 16 + lg * 4;
        int bb = t0g >> 11, t = t0g & 2047;
        short4 pk;
        pk.x = f2bf(acc[i][j][0] + bv);
        pk.y = f2bf(acc[i][j][1] + bv);
        pk.z = f2bf(acc[i][j][2] + bv);
        pk.w = f2bf(acc[i][j][3] + bv);
        *reinterpret_cast<short4*>(&vt[((size_t)(bb * 16 + h) * 64 + d) * 2048 + t]) = pk;
      }
    } else {
      short* dst = (sec == 0) ? qo : ko;
      // q scaled by (1/sqrt(64)) * log2(e) so attention works in exp2 domain
      float sc = (sec == 0) ? 0.18033688f : 1.0f;
      #pragma unroll
      for (int i = 0; i < 4; ++i) {
        #pragma unroll
        for (int r = 0; r < 4; ++r) {
          int m = mtile + wr * 64 + i * 16 + lg * 4 + r;
          int bb = m >> 11, t = m & 2047;
          dst[(size_t)((bb * 16 + h) * 2048 + t) * 64 + d] = f2bf((acc[i][j][r] + bv) * sc);
        }
      }
    }
  }
}

// ---- flash attention v5b: 1 wave per 32-row q-tile, 32x32x16 MFMA, no LDS/barriers,
//      L2-direct K/V streaming, in-register P via cvt_pk + permlane32_swap ----
// S^T = mfma(K,Q): lane owns q-col lq=l&31; kv = (reg&3)+8*(reg>>2)+4*hl.
// PV B-frag for k-step s2 needs kv = 16*s2 + 8*hl + j. permlane32_swap(a,b)
// gives a=[a_lo,b_lo], b=[a_hi,b_hi]  (vdst_hi <-> vsrc_lo), so
// swap(u0,u2), swap(u1,u3) makes {u0,u1,u2,u3} the s2=0 frag in order.
template<int DIAG>
__device__ __forceinline__ void attn_step(const short* __restrict__ kp,
                                          const short* __restrict__ vp,
                                          const bf16x8* qf,
                                          f32x16& y0, f32x16& y1,
                                          float& m, float& li,
                                          int lq, int hl) {
  f32x16 s;
  #pragma unroll
  for (int r = 0; r < 16; ++r) s[r] = 0.f;
  __builtin_amdgcn_s_setprio(1);
  #pragma unroll
  for (int ks = 0; ks < 4; ++ks) {
    bf16x8 kf = *reinterpret_cast<const bf16x8*>(kp + ks * 16);
    s = __builtin_amdgcn_mfma_f32_32x32x16_bf16(kf, qf[ks], s, 0, 0, 0);
  }
  __builtin_amdgcn_s_setprio(0);
  if (DIAG) {
    #pragma unroll
    for (int r = 0; r < 16; ++r) {
      int kvl = (r & 3) + 8 * (r >> 2) + 4 * hl;
      if (kvl > lq) s[r] = -1e30f;
    }
  }
  // row max: 16-reg tree + one half-swap shuffle
  float a0 = fmaxf(fmaxf(s[0], s[1]), fmaxf(s[2], s[3]));
  float a1 = fmaxf(fmaxf(s[4], s[5]), fmaxf(s[6], s[7]));
  float a2 = fmaxf(fmaxf(s[8], s[9]), fmaxf(s[10], s[11]));
  float a3 = fmaxf(fmaxf(s[12], s[13]), fmaxf(s[14], s[15]));
  float pm = fmaxf(fmaxf(a0, a1), fmaxf(a2, a3));
  pm = fmaxf(pm, __shfl_xor(pm, 32));
  // defer-max (T13): rescale only when tile max grew past threshold (log2 units)
  if (!__all(pm - m <= 8.0f)) {
    float mn = fmaxf(m, pm);
    float sc = __builtin_amdgcn_exp2f(m - mn);
    m = mn;
    li *= sc;
    #pragma unroll
    for (int r = 0; r < 16; ++r) { y0[r] *= sc; y1[r] *= sc; }
  }
  // p = exp2(s - m), packed pairs; u[rq*2+h] covers kv pair {8rq+4hl+2h, +1}
  unsigned u[8];
  float rs = 0.f;
  #pragma unroll
  for (int rq = 0; rq < 4; ++rq) {
    float p0 = __builtin_amdgcn_exp2f(s[4 * rq + 0] - m);
    float p1 = __builtin_amdgcn_exp2f(s[4 * rq + 1] - m);
    float p2 = __builtin_amdgcn_exp2f(s[4 * rq + 2] - m);
    float p3 = __builtin_amdgcn_exp2f(s[4 * rq + 3] - m);
    rs += (p0 + p1) + (p2 + p3);
    asm("v_cvt_pk_bf16_f32 %0, %1, %2" : "=v"(u[rq * 2 + 0]) : "v"(p0), "v"(p1));
    asm("v_cvt_pk_bf16_f32 %0, %1, %2" : "=v"(u[rq * 2 + 1]) : "v"(p2), "v"(p3));
  }
  rs += __shfl_xor(rs, 32);
  li += rs;
  // half-swaps (vdst = LOW-kv word, vsrc = the +8kv word): after these,
  // {u[0..3]} is the s2=0 B-frag, {u[4..7]} the s2=1 B-frag, in word order.
  asm volatile("v_permlane32_swap_b32 %0, %1" : "+v"(u[0]), "+v"(u[2]));
  asm volatile("v_permlane32_swap_b32 %0, %1" : "+v"(u[1]), "+v"(u[3]));
  asm volatile("v_permlane32_swap_b32 %0, %1" : "+v"(u[4]), "+v"(u[6]));
  asm volatile("v_permlane32_swap_b32 %0, %1" : "+v"(u[5]), "+v"(u[7]));
  uint32x4 w0 = {u[0], u[1], u[2], u[3]};
  uint32x4 w1 = {u[4], u[5], u[6], u[7]};
  bf16x8 pa0 = __builtin_bit_cast(bf16x8, w0);
  bf16x8 pa1 = __builtin_bit_cast(bf16x8, w1);
  __builtin_amdgcn_s_setprio(1);
  {
    bf16x8 vf00 = *reinterpret_cast<const bf16x8*>(vp);
    bf16x8 vf01 = *reinterpret_cast<const bf16x8*>(vp + 16);
    bf16x8 vf10 = *reinterpret_cast<const bf16x8*>(vp + 32 * 2048);
    bf16x8 vf11 = *reinterpret_cast<const bf16x8*>(vp + 32 * 2048 + 16);
    y0 = __builtin_amdgcn_mfma_f32_32x32x16_bf16(vf00, pa0, y0, 0, 0, 0);
    y0 = __builtin_amdgcn_mfma_f32_32x32x16_bf16(vf01, pa1, y0, 0, 0, 0);
    y1 = __builtin_amdgcn_mfma_f32_32x32x16_bf16(vf10, pa0, y1, 0, 0, 0);
    y1 = __builtin_amdgcn_mfma_f32_32x32x16_bf16(vf11, pa1, y1, 0, 0, 0);
  }
  __builtin_amdgcn_s_setprio(0);
}

__global__ __launch_bounds__(64, 4) void attn_kernel(const short* __restrict__ q,
                                                     const short* __restrict__ k,
                                                     const short* __restrict__ vt,
                                                     short* __restrict__ y) {
  const int bid = blockIdx.x;
  const int t = 63 - (bid >> 5);          // longest-first
  const int b5 = bid & 31;
  const int bh = (b5 & 7) * 4 + (b5 >> 3); // group each bh's waves on one XCD
  const int l = threadIdx.x;
  const int lq = l & 31, hl = l >> 5;
  const short* qb = q + (size_t)bh * 131072;
  const short* kb = k + (size_t)bh * 131072;
  const short* vb = vt + (size_t)bh * 131072;   // [64][2048]

  // Q B-frags (k=64 -> 4 frags), persistent
  bf16x8 qf[4];
  {
    const short* qp = &qb[(size_t)(32 * t + lq) * 64 + hl * 8];
    #pragma unroll
    for (int ks = 0; ks < 4; ++ks)
      qf[ks] = *reinterpret_cast<const bf16x8*>(qp + ks * 16);
  }

  f32x16 y0, y1;
  #pragma unroll
  for (int r = 0; r < 16; ++r) { y0[r] = 0.f; y1[r] = 0.f; }
  float m = -1e30f, li = 0.f;

  const short* kp = kb + (size_t)lq * 64 + hl * 8;   // += 32*64 per tile
  const short* vp = vb + (size_t)lq * 2048 + hl * 8; // += 32 per tile

  for (int it = 0; it < t; ++it) {
    attn_step<0>(kp, vp, qf, y0, y1, m, li, lq, hl);
    kp += 32 * 64;
    vp += 32;
  }
  attn_step<1>(kp, vp, qf, y0, y1, m, li, lq, hl);

  // epilogue: y[b][row][h*64 + d], lane holds q-row 32t+lq, 32 of 64 d-values
  float inv = 1.0f / li;
  int b_ = bh >> 4, h_ = bh & 15;
  short* yrow = &y[(size_t)(b_ * 2048 + 32 * t + lq) * 1024 + h_ * 64];
  #pragma unroll
  for (int dt = 0; dt < 2; ++dt) {
    const f32x16& yy = dt ? y1 : y0;
    #pragma unroll
    for (int rq = 0; rq < 4; ++rq) {
      int d0 = dt * 32 + 8 * rq + 4 * hl;
      uint2 pk;
      pk.x = (unsigned)(unsigned short)f2bf(yy[4 * rq + 0] * inv) |
             ((unsigned)(unsigned short)f2bf(yy[4 * rq + 1] * inv) << 16);
      pk.y = (unsigned)(unsigned short)f2bf(yy[4 * rq + 2] * inv) |
             ((unsigned)(unsigned short)f2bf(yy[4 * rq + 3] * inv) << 16);
      *reinterpret_cast<uint2*>(yrow + d0) = pk;
    }
  }
}

// ---- GEMM3: out fp32 = y_bf[4096][1024] * Wproj_t[1024][1024]^T + bproj ----
__global__ __launch_bounds__(256) void gemm_proj(const short* __restrict__ A,
                                                 const short* __restrict__ Bt,
                                                 const float* __restrict__ bias,
                                                 float* __restrict__ out) {
  const int K = 1024;
  __shared__ short Al[8192];
  __shared__ short Bl[8192];
  int tid = threadIdx.x;
  int mtile = blockIdx.y * 128, ntile = blockIdx.x * 128;
  int w = tid >> 6, l = tid & 63;
  int wr = w >> 1, wc = w & 1;
  int lr = l & 15, lg = l >> 4;

  f32x4 zero4 = {0.f, 0.f, 0.f, 0.f};
  f32x4 acc[4][4];
  #pragma unroll
  for (int i = 0; i < 4; ++i)
    #pragma unroll
    for (int j = 0; j < 4; ++j) acc[i][j] = zero4;

  for (int k0 = 0; k0 < K; k0 += 64) {
    __syncthreads();
    #pragma unroll
    for (int c = 0; c < 4; ++c) {
      int idx = tid + c * 256;
      int row = idx >> 3, kc = idx & 7;
      gl_lds16(&A[(size_t)(mtile + row) * K + k0 + kc * 8], &Al[idx * 8]);
      gl_lds16(&Bt[(size_t)(ntile + row) * K + k0 + kc * 8], &Bl[idx * 8]);
    }
    __syncthreads();
    __builtin_amdgcn_s_setprio(1);
    #pragma unroll
    for (int kk = 0; kk < 2; ++kk) {
      bf16x8 af[4], bfr[4];
      #pragma unroll
      for (int i = 0; i < 4; ++i)
        af[i] = *reinterpret_cast<const bf16x8*>(&Al[(wr * 64 + i * 16 + lr) * 64 + kk * 32 + lg * 8]);
      #pragma unroll
      for (int j = 0; j < 4; ++j)
        bfr[j] = *reinterpret_cast<const bf16x8*>(&Bl[(wc * 64 + j * 16 + lr) * 64 + kk * 32 + lg * 8]);
      #pragma unroll
      for (int i = 0; i < 4; ++i)
        #pragma unroll
        for (int j = 0; j < 4; ++j)
          acc[i][j] = __builtin_amdgcn_mfma_f32_16x16x32_bf16(af[i], bfr[j], acc[i][j], 0, 0, 0);
    }
    __builtin_amdgcn_s_setprio(0);
  }

  #pragma unroll
  for (int j = 0; j < 4; ++j) {
    int n = ntile + wc * 64 + j * 16 + lr;
    float bv = bias[n];
    #pragma unroll
    for (int i = 0; i < 4; ++i) {
      #pragma unroll
      for (int r = 0; r < 4; ++r) {
        int m = mtile + wr * 64 + i * 16 + lg * 4 + r;
        out[(size_t)m * 1024 + n] = acc[i][j][r] + bv;
      }
    }
  }
}

extern "C" void kernel_launch(void* const* d_in, const int* in_sizes, int n_in,
                              void* d_out, int out_size, void* d_ws, size_t ws_size,
                              hipStream_t stream) {
  const float* x     = (const float*)d_in[0];
  const float* Wqkv  = (const float*)d_in[1];
  const float* bqkv  = (const float*)d_in[2];
  const float* Wproj = (const float*)d_in[3];
  const float* bproj = (const float*)d_in[4];
  float* out = (float*)d_out;

  const size_t M4 = 4096ull * 1024ull;
  short* ws = (short*)d_ws;
  short* x_bf    = ws;
  short* wqkv_t  = ws + M4;
  short* wproj_t = ws + M4 + 3ull * 1024 * 1024;
  short* qb      = wproj_t + 1024ull * 1024;
  short* kb      = qb + M4;
  short* vtb     = kb + M4;     // [bh][64][2048] transposed V
  short* yb      = x_bf;        // alias: x_bf dead after gemm_qkv

  cast_x_kernel<<<4096, 256, 0, stream>>>(x, x_bf, (int)(M4 / 4));
  transpose_cast<<<dim3(48, 16), 256, 0, stream>>>(Wqkv, wqkv_t, 1024, 3072);
  transpose_cast<<<dim3(16, 16), 256, 0, stream>>>(Wproj, wproj_t, 1024, 1024);
  gemm_qkv<<<dim3(24, 32), 256, 0, stream>>>(x_bf, wqkv_t, bqkv, qb, kb, vtb);
  attn_kernel<<<2048, 64, 0, stream>>>(qb, kb, vtb, yb);
  gemm_proj<<<dim3(8, 32), 256, 0, stream>>>(yb, wproj_t, bproj, out);
}

// Round 7
// 162.948 us; speedup vs baseline: 1.1286x; 1.1175x over previous
//
#include <hip/hip_runtime.h>

// ---- types ----
typedef __bf16 bf16x8 __attribute__((ext_vector_type(8)));
typedef float  f32x4  __attribute__((ext_vector_type(4)));
typedef float  f32x16 __attribute__((ext_vector_type(16)));
typedef unsigned int uint32x4 __attribute__((ext_vector_type(4)));

__device__ __forceinline__ short f2bf(float f) {
  union { float f; unsigned u; } v; v.f = f;
  unsigned r = v.u + 0x7fffu + ((v.u >> 16) & 1u);
  return (short)(r >> 16);
}

// async global->LDS (16B per lane); LDS dest must be wave-uniform base + lane*16
__device__ __forceinline__ void gl_lds16(const short* g, short* l) {
  __builtin_amdgcn_global_load_lds((const __attribute__((address_space(1))) void*)g,
                                   (__attribute__((address_space(3))) void*)l, 16, 0, 0);
}

// ---- cast x fp32 -> bf16 (vectorized) ----
__global__ __launch_bounds__(256) void cast_x_kernel(const float* __restrict__ in,
                                                     short* __restrict__ out, int n4) {
  int i = blockIdx.x * 256 + threadIdx.x;
  if (i >= n4) return;
  float4 f = reinterpret_cast<const float4*>(in)[i];
  short4 o;
  o.x = f2bf(f.x); o.y = f2bf(f.y); o.z = f2bf(f.z); o.w = f2bf(f.w);
  reinterpret_cast<short4*>(out)[i] = o;
}

// ---- transpose + cast: in[R][Cc] fp32 -> out[Cc][R] bf16 ----
__global__ __launch_bounds__(256) void transpose_cast(const float* __restrict__ in,
                                                      short* __restrict__ out, int R, int Cc) {
  __shared__ short tile[64][65];
  int bx = blockIdx.x * 64;
  int by = blockIdx.y * 64;
  int tx = threadIdx.x & 63, ty = threadIdx.x >> 6;
  #pragma unroll
  for (int i = ty; i < 64; i += 4)
    tile[i][tx] = f2bf(in[(size_t)(by + i) * Cc + bx + tx]);
  __syncthreads();
  #pragma unroll
  for (int i = ty; i < 64; i += 4)
    out[(size_t)(bx + i) * R + by + tx] = tile[tx][i];
}

// ---- GEMM1: qkv = x_bf[4096][1024] * Wqkv_t[3072][1024]^T + bqkv
//      q,k -> [B2][H16][T2048][D64] bf16 (q scaled 0.125*log2e); v -> [BH][D64][T2048]
__global__ __launch_bounds__(256) void gemm_qkv(const short* __restrict__ A,
                                                const short* __restrict__ Bt,
                                                const float* __restrict__ bias,
                                                short* __restrict__ qo,
                                                short* __restrict__ ko,
                                                short* __restrict__ vt) {
  const int K = 1024;
  __shared__ short Al[8192];   // linear [128][64]
  __shared__ short Bl[8192];
  int tid = threadIdx.x;
  int mtile = blockIdx.y * 128, ntile = blockIdx.x * 128;
  int w = tid >> 6, l = tid & 63;
  int wr = w >> 1, wc = w & 1;
  int lr = l & 15, lg = l >> 4;

  f32x4 zero4 = {0.f, 0.f, 0.f, 0.f};
  f32x4 acc[4][4];
  #pragma unroll
  for (int i = 0; i < 4; ++i)
    #pragma unroll
    for (int j = 0; j < 4; ++j) acc[i][j] = zero4;

  for (int k0 = 0; k0 < K; k0 += 64) {
    __syncthreads();
    #pragma unroll
    for (int c = 0; c < 4; ++c) {
      int idx = tid + c * 256;
      int row = idx >> 3, kc = idx & 7;
      gl_lds16(&A[(size_t)(mtile + row) * K + k0 + kc * 8], &Al[idx * 8]);
      gl_lds16(&Bt[(size_t)(ntile + row) * K + k0 + kc * 8], &Bl[idx * 8]);
    }
    __syncthreads();
    __builtin_amdgcn_s_setprio(1);
    #pragma unroll
    for (int kk = 0; kk < 2; ++kk) {
      bf16x8 af[4], bfr[4];
      #pragma unroll
      for (int i = 0; i < 4; ++i)
        af[i] = *reinterpret_cast<const bf16x8*>(&Al[(wr * 64 + i * 16 + lr) * 64 + kk * 32 + lg * 8]);
      #pragma unroll
      for (int j = 0; j < 4; ++j)
        bfr[j] = *reinterpret_cast<const bf16x8*>(&Bl[(wc * 64 + j * 16 + lr) * 64 + kk * 32 + lg * 8]);
      #pragma unroll
      for (int i = 0; i < 4; ++i)
        #pragma unroll
        for (int j = 0; j < 4; ++j)
          acc[i][j] = __builtin_amdgcn_mfma_f32_16x16x32_bf16(af[i], bfr[j], acc[i][j], 0, 0, 0);
    }
    __builtin_amdgcn_s_setprio(0);
  }

  #pragma unroll
  for (int j = 0; j < 4; ++j) {
    int n = ntile + wc * 64 + j * 16 + lr;   // 0..3071 (sec uniform per block)
    float bv = bias[n];
    int sec = n >> 10;
    int ch = n & 1023;
    int h = ch >> 6, d = ch & 63;
    if (sec == 2) {
      #pragma unroll
      for (int i = 0; i < 4; ++i) {
        int t0g = mtile + wr * 64 + i * 16 + lg * 4;
        int bb = t0g >> 11, t = t0g & 2047;
        short4 pk;
        pk.x = f2bf(acc[i][j][0] + bv);
        pk.y = f2bf(acc[i][j][1] + bv);
        pk.z = f2bf(acc[i][j][2] + bv);
        pk.w = f2bf(acc[i][j][3] + bv);
        *reinterpret_cast<short4*>(&vt[((size_t)(bb * 16 + h) * 64 + d) * 2048 + t]) = pk;
      }
    } else {
      short* dst = (sec == 0) ? qo : ko;
      // q scaled by (1/sqrt(64)) * log2(e) so attention works in exp2 domain
      float sc = (sec == 0) ? 0.18033688f : 1.0f;
      #pragma unroll
      for (int i = 0; i < 4; ++i) {
        #pragma unroll
        for (int r = 0; r < 4; ++r) {
          int m = mtile + wr * 64 + i * 16 + lg * 4 + r;
          int bb = m >> 11, t = m & 2047;
          dst[(size_t)((bb * 16 + h) * 2048 + t) * 64 + d] = f2bf((acc[i][j][r] + bv) * sc);
        }
      }
    }
  }
}

// ---- flash attention v6: 4 waves/block split the KV range of ONE 32-row q-tile,
//      each wave = v5b in-register pipeline (32x32x16, cvt_pk+permlane32_swap),
//      LDS merge of the 4 partials at the end ----
template<int DIAG>
__device__ __forceinline__ void attn_step(const short* __restrict__ kp,
                                          const short* __restrict__ vp,
                                          const bf16x8* qf,
                                          f32x16& y0, f32x16& y1,
                                          float& m, float& li,
                                          int lq, int hl) {
  f32x16 s;
  #pragma unroll
  for (int r = 0; r < 16; ++r) s[r] = 0.f;
  __builtin_amdgcn_s_setprio(1);
  #pragma unroll
  for (int ks = 0; ks < 4; ++ks) {
    bf16x8 kf = *reinterpret_cast<const bf16x8*>(kp + ks * 16);
    s = __builtin_amdgcn_mfma_f32_32x32x16_bf16(kf, qf[ks], s, 0, 0, 0);
  }
  __builtin_amdgcn_s_setprio(0);
  if (DIAG) {
    #pragma unroll
    for (int r = 0; r < 16; ++r) {
      int kvl = (r & 3) + 8 * (r >> 2) + 4 * hl;
      if (kvl > lq) s[r] = -1e30f;
    }
  }
  float a0 = fmaxf(fmaxf(s[0], s[1]), fmaxf(s[2], s[3]));
  float a1 = fmaxf(fmaxf(s[4], s[5]), fmaxf(s[6], s[7]));
  float a2 = fmaxf(fmaxf(s[8], s[9]), fmaxf(s[10], s[11]));
  float a3 = fmaxf(fmaxf(s[12], s[13]), fmaxf(s[14], s[15]));
  float pm = fmaxf(fmaxf(a0, a1), fmaxf(a2, a3));
  pm = fmaxf(pm, __shfl_xor(pm, 32));
  if (!__all(pm - m <= 8.0f)) {
    float mn = fmaxf(m, pm);
    float sc = __builtin_amdgcn_exp2f(m - mn);
    m = mn;
    li *= sc;
    #pragma unroll
    for (int r = 0; r < 16; ++r) { y0[r] *= sc; y1[r] *= sc; }
  }
  unsigned u[8];
  float rs = 0.f;
  #pragma unroll
  for (int rq = 0; rq < 4; ++rq) {
    float p0 = __builtin_amdgcn_exp2f(s[4 * rq + 0] - m);
    float p1 = __builtin_amdgcn_exp2f(s[4 * rq + 1] - m);
    float p2 = __builtin_amdgcn_exp2f(s[4 * rq + 2] - m);
    float p3 = __builtin_amdgcn_exp2f(s[4 * rq + 3] - m);
    rs += (p0 + p1) + (p2 + p3);
    asm("v_cvt_pk_bf16_f32 %0, %1, %2" : "=v"(u[rq * 2 + 0]) : "v"(p0), "v"(p1));
    asm("v_cvt_pk_bf16_f32 %0, %1, %2" : "=v"(u[rq * 2 + 1]) : "v"(p2), "v"(p3));
  }
  rs += __shfl_xor(rs, 32);
  li += rs;
  asm volatile("v_permlane32_swap_b32 %0, %1" : "+v"(u[0]), "+v"(u[2]));
  asm volatile("v_permlane32_swap_b32 %0, %1" : "+v"(u[1]), "+v"(u[3]));
  asm volatile("v_permlane32_swap_b32 %0, %1" : "+v"(u[4]), "+v"(u[6]));
  asm volatile("v_permlane32_swap_b32 %0, %1" : "+v"(u[5]), "+v"(u[7]));
  uint32x4 w0 = {u[0], u[1], u[2], u[3]};
  uint32x4 w1 = {u[4], u[5], u[6], u[7]};
  bf16x8 pa0 = __builtin_bit_cast(bf16x8, w0);
  bf16x8 pa1 = __builtin_bit_cast(bf16x8, w1);
  __builtin_amdgcn_s_setprio(1);
  {
    bf16x8 vf00 = *reinterpret_cast<const bf16x8*>(vp);
    bf16x8 vf01 = *reinterpret_cast<const bf16x8*>(vp + 16);
    bf16x8 vf10 = *reinterpret_cast<const bf16x8*>(vp + 32 * 2048);
    bf16x8 vf11 = *reinterpret_cast<const bf16x8*>(vp + 32 * 2048 + 16);
    y0 = __builtin_amdgcn_mfma_f32_32x32x16_bf16(vf00, pa0, y0, 0, 0, 0);
    y0 = __builtin_amdgcn_mfma_f32_32x32x16_bf16(vf01, pa1, y0, 0, 0, 0);
    y1 = __builtin_amdgcn_mfma_f32_32x32x16_bf16(vf10, pa0, y1, 0, 0, 0);
    y1 = __builtin_amdgcn_mfma_f32_32x32x16_bf16(vf11, pa1, y1, 0, 0, 0);
  }
  __builtin_amdgcn_s_setprio(0);
}

__global__ __launch_bounds__(256, 4) void attn_kernel(const short* __restrict__ q,
                                                      const short* __restrict__ k,
                                                      const short* __restrict__ vt,
                                                      short* __restrict__ y) {
  __shared__ float partL[3][8][64][4];   // 24 KB: partials of waves 1..3
  __shared__ float stm[4][32], stl[4][32];
  const int bid = blockIdx.x;
  const int t = 63 - (bid >> 5);           // longest-first
  const int b5 = bid & 31;
  const int bh = (b5 & 7) * 4 + (b5 >> 3); // group each bh's blocks on one XCD
  const int tid = threadIdx.x;
  const int w = tid >> 6;                  // wave: kv-split index 0..3
  const int l = tid & 63;
  const int lq = l & 31, hl = l >> 5;
  const short* qb = q + (size_t)bh * 131072;
  const short* kb = k + (size_t)bh * 131072;
  const short* vb = vt + (size_t)bh * 131072;   // [64][2048]

  // Q B-frags (k=64 -> 4 frags), shared q-tile for all 4 waves
  bf16x8 qf[4];
  {
    const short* qp = &qb[(size_t)(32 * t + lq) * 64 + hl * 8];
    #pragma unroll
    for (int ks = 0; ks < 4; ++ks)
      qf[ks] = *reinterpret_cast<const bf16x8*>(qp + ks * 16);
  }

  f32x16 y0, y1;
  #pragma unroll
  for (int r = 0; r < 16; ++r) { y0[r] = 0.f; y1[r] = 0.f; }
  float m = -1e30f, li = 0.f;

  // wave w handles kv tiles {w, w+4, ...} < t, plus diag tile t if t&3==w
  const short* kp = kb + (size_t)w * 2048 + (size_t)lq * 64 + hl * 8;
  const short* vp = vb + (size_t)lq * 2048 + w * 32 + hl * 8;
  for (int it = w; it < t; it += 4) {
    attn_step<0>(kp, vp, qf, y0, y1, m, li, lq, hl);
    kp += 4 * 2048;
    vp += 4 * 32;
  }
  if ((t & 3) == w) {
    const short* kpd = kb + (size_t)t * 2048 + (size_t)lq * 64 + hl * 8;
    const short* vpd = vb + (size_t)lq * 2048 + t * 32 + hl * 8;
    attn_step<1>(kpd, vpd, qf, y0, y1, m, li, lq, hl);
  }

  // ---- merge the 4 wave-partials ----
  if (hl == 0) { stm[w][lq] = m; stl[w][lq] = li; }
  __syncthreads();
  float m0 = stm[0][lq], m1 = stm[1][lq], m2 = stm[2][lq], m3 = stm[3][lq];
  float M = fmaxf(fmaxf(m0, m1), fmaxf(m2, m3));
  float L = stl[0][lq] * __builtin_amdgcn_exp2f(m0 - M) +
            stl[1][lq] * __builtin_amdgcn_exp2f(m1 - M) +
            stl[2][lq] * __builtin_amdgcn_exp2f(m2 - M) +
            stl[3][lq] * __builtin_amdgcn_exp2f(m3 - M);
  float sc = __builtin_amdgcn_exp2f(m - M);
  #pragma unroll
  for (int r = 0; r < 16; ++r) { y0[r] *= sc; y1[r] *= sc; }
  if (w > 0) {
    #pragma unroll
    for (int c = 0; c < 4; ++c) {
      f32x4 v0 = {y0[4 * c + 0], y0[4 * c + 1], y0[4 * c + 2], y0[4 * c + 3]};
      f32x4 v1 = {y1[4 * c + 0], y1[4 * c + 1], y1[4 * c + 2], y1[4 * c + 3]};
      *reinterpret_cast<f32x4*>(&partL[w - 1][c][l][0]) = v0;
      *reinterpret_cast<f32x4*>(&partL[w - 1][c + 4][l][0]) = v1;
    }
  }
  __syncthreads();
  if (w == 0) {
    #pragma unroll
    for (int o = 0; o < 3; ++o)
      #pragma unroll
      for (int c = 0; c < 4; ++c) {
        f32x4 v0 = *reinterpret_cast<const f32x4*>(&partL[o][c][l][0]);
        f32x4 v1 = *reinterpret_cast<const f32x4*>(&partL[o][c + 4][l][0]);
        #pragma unroll
        for (int r = 0; r < 4; ++r) { y0[4 * c + r] += v0[r]; y1[4 * c + r] += v1[r]; }
      }
    float inv = 1.0f / L;
    int b_ = bh >> 4, h_ = bh & 15;
    short* yrow = &y[(size_t)(b_ * 2048 + 32 * t + lq) * 1024 + h_ * 64];
    #pragma unroll
    for (int dt = 0; dt < 2; ++dt) {
      const f32x16& yy = dt ? y1 : y0;
      #pragma unroll
      for (int rq = 0; rq < 4; ++rq) {
        int d0 = dt * 32 + 8 * rq + 4 * hl;
        uint2 pk;
        pk.x = (unsigned)(unsigned short)f2bf(yy[4 * rq + 0] * inv) |
               ((unsigned)(unsigned short)f2bf(yy[4 * rq + 1] * inv) << 16);
        pk.y = (unsigned)(unsigned short)f2bf(yy[4 * rq + 2] * inv) |
               ((unsigned)(unsigned short)f2bf(yy[4 * rq + 3] * inv) << 16);
        *reinterpret_cast<uint2*>(yrow + d0) = pk;
      }
    }
  }
}

// ---- GEMM3: out fp32 = y_bf[4096][1024] * Wproj_t[1024][1024]^T + bproj ----
__global__ __launch_bounds__(256) void gemm_proj(const short* __restrict__ A,
                                                 const short* __restrict__ Bt,
                                                 const float* __restrict__ bias,
                                                 float* __restrict__ out) {
  const int K = 1024;
  __shared__ short Al[8192];
  __shared__ short Bl[8192];
  int tid = threadIdx.x;
  int mtile = blockIdx.y * 128, ntile = blockIdx.x * 128;
  int w = tid >> 6, l = tid & 63;
  int wr = w >> 1, wc = w & 1;
  int lr = l & 15, lg = l >> 4;

  f32x4 zero4 = {0.f, 0.f, 0.f, 0.f};
  f32x4 acc[4][4];
  #pragma unroll
  for (int i = 0; i < 4; ++i)
    #pragma unroll
    for (int j = 0; j < 4; ++j) acc[i][j] = zero4;

  for (int k0 = 0; k0 < K; k0 += 64) {
    __syncthreads();
    #pragma unroll
    for (int c = 0; c < 4; ++c) {
      int idx = tid + c * 256;
      int row = idx >> 3, kc = idx & 7;
      gl_lds16(&A[(size_t)(mtile + row) * K + k0 + kc * 8], &Al[idx * 8]);
      gl_lds16(&Bt[(size_t)(ntile + row) * K + k0 + kc * 8], &Bl[idx * 8]);
    }
    __syncthreads();
    __builtin_amdgcn_s_setprio(1);
    #pragma unroll
    for (int kk = 0; kk < 2; ++kk) {
      bf16x8 af[4], bfr[4];
      #pragma unroll
      for (int i = 0; i < 4; ++i)
        af[i] = *reinterpret_cast<const bf16x8*>(&Al[(wr * 64 + i * 16 + lr) * 64 + kk * 32 + lg * 8]);
      #pragma unroll
      for (int j = 0; j < 4; ++j)
        bfr[j] = *reinterpret_cast<const bf16x8*>(&Bl[(wc * 64 + j * 16 + lr) * 64 + kk * 32 + lg * 8]);
      #pragma unroll
      for (int i = 0; i < 4; ++i)
        #pragma unroll
        for (int j = 0; j < 4; ++j)
          acc[i][j] = __builtin_amdgcn_mfma_f32_16x16x32_bf16(af[i], bfr[j], acc[i][j], 0, 0, 0);
    }
    __builtin_amdgcn_s_setprio(0);
  }

  #pragma unroll
  for (int j = 0; j < 4; ++j) {
    int n = ntile + wc * 64 + j * 16 + lr;
    float bv = bias[n];
    #pragma unroll
    for (int i = 0; i < 4; ++i) {
      #pragma unroll
      for (int r = 0; r < 4; ++r) {
        int m = mtile + wr * 64 + i * 16 + lg * 4 + r;
        out[(size_t)m * 1024 + n] = acc[i][j][r] + bv;
      }
    }
  }
}

extern "C" void kernel_launch(void* const* d_in, const int* in_sizes, int n_in,
                              void* d_out, int out_size, void* d_ws, size_t ws_size,
                              hipStream_t stream) {
  const float* x     = (const float*)d_in[0];
  const float* Wqkv  = (const float*)d_in[1];
  const float* bqkv  = (const float*)d_in[2];
  const float* Wproj = (const float*)d_in[3];
  const float* bproj = (const float*)d_in[4];
  float* out = (float*)d_out;

  const size_t M4 = 4096ull * 1024ull;
  short* ws = (short*)d_ws;
  short* x_bf    = ws;
  short* wqkv_t  = ws + M4;
  short* wproj_t = ws + M4 + 3ull * 1024 * 1024;
  short* qb      = wproj_t + 1024ull * 1024;
  short* kb      = qb + M4;
  short* vtb     = kb + M4;     // [bh][64][2048] transposed V
  short* yb      = x_bf;        // alias: x_bf dead after gemm_qkv

  cast_x_kernel<<<4096, 256, 0, stream>>>(x, x_bf, (int)(M4 / 4));
  transpose_cast<<<dim3(48, 16), 256, 0, stream>>>(Wqkv, wqkv_t, 1024, 3072);
  transpose_cast<<<dim3(16, 16), 256, 0, stream>>>(Wproj, wproj_t, 1024, 1024);
  gemm_qkv<<<dim3(24, 32), 256, 0, stream>>>(x_bf, wqkv_t, bqkv, qb, kb, vtb);
  attn_kernel<<<2048, 256, 0, stream>>>(qb, kb, vtb, yb);
  gemm_proj<<<dim3(8, 32), 256, 0, stream>>>(yb, wproj_t, bproj, out);
}